// Round 5
// baseline (515.335 us; speedup 1.0000x reference)
//
#include <hip/hip_runtime.h>

// SCF GRU layer: T=40 steps, B=128 batches, N=64 agents/batch, H=48 hidden.
// BN = 8192 rows. DIN = 52 = loc(2) + rel(2) + vel(16) + img_feat(32).
//
// Decomposition (2 launches):
//  k_pre : blocks [0,4096)    -> img_feat[b][c] = mean over 80x80 of f_img (HBM-bound, 105 MB)
//          blocks [4096,5376) -> S[t][b][2] = sum of locs over the 64 agents (4 (t,b) per block)
//  k_gru : per-row independent 40-step recurrence. 192 threads/row:
//          thread = (gate/hidden j in [0,48), K-quarter s in [0,4)).
//          History: 96-thr/row needed 102 weight floats/thread; the allocator's
//          arch-VGPR budget is 84 (unified-file even split once AGPRs appear),
//          so weights spilled to AGPRs -> ~100 v_accvgpr_read VALU copies per
//          step (measured ~339 VALU instr/wave-step vs ~150 source; 238us).
//          QUARTER-K split cuts weights to 51 floats/thread so total demand
//          (~85) fits the arch budget -> no per-step copies.
//          4-lane butterfly (shfl_xor 1,2) reduces the K-quarters.
//          h and x double-buffered in LDS -> ONE barrier per step.
//          Global loads for step t+1 prefetched into registers before the barrier.
//
// (Round 4 was an infra failure -- "container failed twice", no measurement;
//  kernel re-audited for races/hangs and resubmitted unchanged.)

#define T_STEPS 40
#define BB      128
#define NN      64
#define HH      48
#define BN      8192
#define G3      144   // 3*H

#define KEEP1(x) asm volatile("" : "+v"(x))
#define KEEP2(v) do { KEEP1((v).x); KEEP1((v).y); } while (0)

__device__ __forceinline__ float sigmoid_(float x) {
    return __builtin_amdgcn_rcpf(1.0f + __expf(-x));
}

__global__ __launch_bounds__(256) void k_pre(const float* __restrict__ f_img,
                                             const float* __restrict__ path,
                                             float* __restrict__ img_out,
                                             float* __restrict__ S) {
    if (blockIdx.x < 4096) {
        // ---- per-(b,c) image mean over 80x80 = 1600 float4 ----
        const int bc = blockIdx.x;
        const float4* p = reinterpret_cast<const float4*>(f_img + (size_t)bc * 6400);
        float s = 0.0f;
        for (int i = threadIdx.x; i < 1600; i += 256) {
            float4 v = p[i];
            s += v.x + v.y + v.z + v.w;
        }
        for (int off = 32; off > 0; off >>= 1) s += __shfl_down(s, off, 64);
        __shared__ float red[4];
        const int wid = threadIdx.x >> 6, lane = threadIdx.x & 63;
        if (lane == 0) red[wid] = s;
        __syncthreads();
        if (threadIdx.x == 0)
            img_out[bc] = (red[0] + red[1] + red[2] + red[3]) * (1.0f / 6400.0f);
    } else {
        // ---- loc sums: one (t,b) per wave, 4 waves/block ----
        const int tb   = (blockIdx.x - 4096) * 4 + (threadIdx.x >> 6);  // t*128 + b
        const int lane = threadIdx.x & 63;
        const float2 v = reinterpret_cast<const float2*>(path)[(size_t)tb * 64 + lane];
        float sx = v.x, sy = v.y;
        for (int off = 32; off > 0; off >>= 1) {
            sx += __shfl_down(sx, off, 64);
            sy += __shfl_down(sy, off, 64);
        }
        if (lane == 0) {
            float2 o; o.x = sx; o.y = sy;
            reinterpret_cast<float2*>(S)[tb] = o;
        }
    }
}

// Main recurrence. Block = 192 threads = 1 row.
// lane q = j*4 + s : j = gate/hidden index, s = K-quarter.
// shfl_xor(1) and shfl_xor(2) reduce across the 4 quarter lanes (4-aligned
// groups within a wave -> DPP quad-perm, cheap).
__global__ __attribute__((amdgpu_waves_per_eu(3, 3)))
__launch_bounds__(192) void k_gru(const float* __restrict__ path,
                                  const float* __restrict__ f_vel,
                                  const float* __restrict__ W_ih,
                                  const float* __restrict__ W_hh,
                                  const float* __restrict__ b_ih,
                                  const float* __restrict__ b_hh,
                                  const float* __restrict__ img,
                                  const float* __restrict__ S,
                                  float* __restrict__ out) {
    const int tid = threadIdx.x;
    const int j   = tid >> 2;        // gate/hidden index 0..47
    const int s   = tid & 3;         // K-quarter
    const int row = blockIdx.x;
    const int b   = row >> 6;        // batch = row / 64

    __shared__ float sh[2][HH];      // [buf][j]  hidden state, double-buffered
    __shared__ float sx[2][20];      // [buf][.]  time-varying input, double-buffered
    __shared__ float g0sh[G3];       // per-batch time-invariant gi part

    // ---- G0 prologue: g0[g] = b_ih[g] + img_feat[b] . W_ih[g, 20:52] ----
    if (tid < G3) {
        float acc = b_ih[tid];
        const float* w  = W_ih + tid * 52 + 20;
        const float* im = img + b * 32;
#pragma unroll
        for (int c = 0; c < 32; ++c) acc = fmaf(im[c], w[c], acc);
        g0sh[tid] = acc;
    }

    // ---- weight quarter-slices into registers ----
    // x-part: 5 scalars per gate (cols s*5 .. s*5+4 of the 20 time-varying inputs)
    float wihr[5], wihz[5], wihn[5];
    {
        const float* wr = W_ih + (j)      * 52 + s * 5;
        const float* wz = W_ih + (48 + j) * 52 + s * 5;
        const float* wn = W_ih + (96 + j) * 52 + s * 5;
#pragma unroll
        for (int p = 0; p < 5; ++p) { wihr[p] = wr[p]; wihz[p] = wz[p]; wihn[p] = wn[p]; }
    }
    // h-part: 6 float2 per gate (cols s*12 .. s*12+11 of the 48 hidden)
    float2 whhr[6], whhz[6], whhn[6];
    {
        const float2* hr = reinterpret_cast<const float2*>(W_hh + (j)      * 48 + s * 12);
        const float2* hz = reinterpret_cast<const float2*>(W_hh + (48 + j) * 48 + s * 12);
        const float2* hn_ = reinterpret_cast<const float2*>(W_hh + (96 + j) * 48 + s * 12);
#pragma unroll
        for (int p = 0; p < 6; ++p) { whhr[p] = hr[p]; whhz[p] = hz[p]; whhn[p] = hn_[p]; }
    }
    // ---- PIN weights into VGPRs (forbid remat/reload) ----
#pragma unroll
    for (int p = 0; p < 5; ++p) { KEEP1(wihr[p]); KEEP1(wihz[p]); KEEP1(wihn[p]); }
#pragma unroll
    for (int p = 0; p < 6; ++p) { KEEP2(whhr[p]); KEEP2(whhz[p]); KEEP2(whhn[p]); }

    float bhn = b_hh[96 + j];
    const float bhr = b_hh[j], bhz = b_hh[48 + j];

    if (tid < HH) sh[0][tid] = 0.0f;   // h0 = 0

    // ---- prefetch step-0 inputs into registers ----
    float  vcur = 0.0f, vnxt = 0.0f;
    float2 lcur = {0.f, 0.f}, lnxt = {0.f, 0.f};
    float2 scur = {0.f, 0.f}, snxt = {0.f, 0.f};
    if (tid < 16) {
        vcur = f_vel[(size_t)row * 16 + tid];
    } else if (tid == 16) {
        lcur = reinterpret_cast<const float2*>(path)[row];
        scur = reinterpret_cast<const float2*>(S)[b];
    }

    __syncthreads();   // g0sh + sh[0] ready
    // fold b_hh r/z into the per-thread gate constants
    float cr  = g0sh[j]      + bhr;
    float cz  = g0sh[48 + j] + bhz;
    float g0n = g0sh[96 + j];
    KEEP1(cr); KEEP1(cz); KEEP1(g0n); KEEP1(bhn);

    float hp = 0.0f;   // h_prev for this j (all 4 quarter lanes identical)
    int p = 0;
    for (int t = 0; t < T_STEPS; ++t) {
        // ---- stage x[t] (held in regs) into LDS buffer p ----
        if (tid < 16) {
            sx[p][4 + tid] = vcur;
        } else if (tid == 16) {
            sx[p][0] = lcur.x;
            sx[p][1] = lcur.y;
            sx[p][2] = (scur.x - 64.0f * lcur.x) * (1.0f / 63.0f);  // rel = (S-64*loc)/63
            sx[p][3] = (scur.y - 64.0f * lcur.y) * (1.0f / 63.0f);
        }
        // ---- prefetch t+1 (latency hides under this step's compute) ----
        if (t + 1 < T_STEPS) {
            if (tid < 16) {
                vnxt = f_vel[((size_t)(t + 1) * BN + row) * 16 + tid];
            } else if (tid == 16) {
                lnxt = reinterpret_cast<const float2*>(path)[(size_t)(t + 1) * BN + row];
                snxt = reinterpret_cast<const float2*>(S)[(t + 1) * BB + b];
            }
        }
        __syncthreads();   // sx[p] staged, sh[p] (written last step) visible

        // ---- x-part: 5 scalar FMAs per gate (broadcast LDS reads) ----
        const float* xq = &sx[p][s * 5];
        float arx = 0.0f, azx = 0.0f, anx = 0.0f;
#pragma unroll
        for (int pp = 0; pp < 5; ++pp) {
            const float xv = xq[pp];
            arx = fmaf(xv, wihr[pp], arx);
            azx = fmaf(xv, wihz[pp], azx);
            anx = fmaf(xv, wihn[pp], anx);
        }
        // ---- h-part: 6 float2 FMAs per gate ----
        const float2* hq = reinterpret_cast<const float2*>(&sh[p][s * 12]);
        float2 ar2 = {0.f, 0.f}, az2 = {0.f, 0.f}, an2 = {0.f, 0.f};
#pragma unroll
        for (int pp = 0; pp < 6; ++pp) {
            const float2 hv = hq[pp];
            ar2.x = fmaf(hv.x, whhr[pp].x, ar2.x); ar2.y = fmaf(hv.y, whhr[pp].y, ar2.y);
            az2.x = fmaf(hv.x, whhz[pp].x, az2.x); az2.y = fmaf(hv.y, whhz[pp].y, az2.y);
            an2.x = fmaf(hv.x, whhn[pp].x, an2.x); an2.y = fmaf(hv.y, whhn[pp].y, an2.y);
        }
        // ---- butterfly reduce across the 4 quarter lanes ----
        float sr  = arx + ar2.x + ar2.y;
        float szv = azx + az2.x + az2.y;
        float sni = anx;
        float snh = an2.x + an2.y;
        sr  += __shfl_xor(sr, 1, 64);  sr  += __shfl_xor(sr, 2, 64);
        szv += __shfl_xor(szv, 1, 64); szv += __shfl_xor(szv, 2, 64);
        sni += __shfl_xor(sni, 1, 64); sni += __shfl_xor(sni, 2, 64);
        snh += __shfl_xor(snh, 1, 64); snh += __shfl_xor(snh, 2, 64);

        const float rg = sigmoid_(sr + cr);
        const float zg = sigmoid_(szv + cz);
        float a = (sni + g0n) + rg * (snh + bhn);
        a = fminf(fmaxf(a, -15.0f), 15.0f);
        const float e = __expf(-2.0f * a);
        const float cand = (1.0f - e) * __builtin_amdgcn_rcpf(1.0f + e);
        const float hn = zg * (hp - cand) + cand;   // (1-z)*cand + z*h

        // write to the OTHER buffer -> no pre-write barrier needed
        if (s == 0) {
            sh[p ^ 1][j] = hn;
        } else if (s == 1) {
            out[((size_t)t * BN + row) * HH + j] = hn;
        } else if (s == 2 && t == T_STEPS - 1) {
            out[(size_t)T_STEPS * BN * HH + (size_t)row * HH + j] = hn;  // hT
        }
        hp = hn;
        vcur = vnxt; lcur = lnxt; scur = snxt;
        p ^= 1;
    }
}

extern "C" void kernel_launch(void* const* d_in, const int* in_sizes, int n_in,
                              void* d_out, int out_size, void* d_ws, size_t ws_size,
                              hipStream_t stream) {
    const float* path  = (const float*)d_in[0];
    const float* f_vel = (const float*)d_in[1];
    const float* f_img = (const float*)d_in[2];
    const float* W_ih  = (const float*)d_in[3];
    const float* W_hh  = (const float*)d_in[4];
    const float* b_ih  = (const float*)d_in[5];
    const float* b_hh  = (const float*)d_in[6];
    float* out = (float*)d_out;

    float* ws  = (float*)d_ws;
    float* img = ws;                  // 4096 floats
    float* S   = ws + 4096;           // 10240 floats (float2-aligned: 16 KB offset)

    // img_mean blocks [0,4096) + ssum blocks [4096, 4096+1280)
    hipLaunchKernelGGL(k_pre, dim3(4096 + (T_STEPS * BB) / 4), dim3(256), 0, stream,
                       f_img, path, img, S);
    hipLaunchKernelGGL(k_gru, dim3(BN), dim3(192), 0, stream,
                       path, f_vel, W_ih, W_hh, b_ih, b_hh, img, S, out);
}

// Round 7
// 474.116 us; speedup vs baseline: 1.0869x; 1.0869x over previous
//
#include <hip/hip_runtime.h>

// SCF GRU layer: T=40 steps, B=128 batches, N=64 agents/batch, H=48 hidden.
// BN = 8192 rows. DIN = 52 = loc(2) + rel(2) + vel(16) + img_feat(32).
//
// KEY LESSON (R0-R5 counters): __syncthreads() drains vmcnt(0) on gfx950.
// Any global load/store issued inside the t-loop is force-completed at the
// per-step barrier -> each step serializes a full HBM round trip (~2000 cyc
// of the measured ~2680 cyc/step). FIX: ZERO global memory ops inside the
// t-loop. Inputs are staged to LDS in the prologue; outputs buffered in LDS
// and flushed after the loop. The per-step barrier then drains only LDS.
//
// Decomposition (3 launches, workspace = 128 KB as in the known-good rounds):
//  k_pre : blocks [0,4096)    -> img_feat[b][c] = mean over 80x80 of f_img
//          blocks [4096,5376) -> S[t][b][2] = sum of locs over the 64 agents
//  k_g0  : G0[b][g] = b_ih[g] + (g<96 ? b_hh[g] : 0) + img[b].W_ih[g,20:52]
//  k_gru : 2 rows/block, 384 threads; per row 192 threads = (j in [0,48),
//          K-quarter s in [0,4)). Per-thread weights = 51 floats (fits the
//          allocator's ~84-96 arch-VGPR budget -> no AGPR shelving copies).
//          rel = (S-64*loc)/63 folds into W' = W[:,0:2]-(64/63)W[:,2:4] plus a
//          batch-uniform S-term, precomputed per (t,g) into LDS (gb) in the
//          prologue. 4-lane butterfly (shfl_xor 1,2) reduces the K-quarters.

#define T_STEPS 40
#define BB      128
#define NN      64
#define HH      48
#define BN      8192
#define G3      144   // 3*H

#define KEEP1(x) asm volatile("" : "+v"(x))
#define KEEP2(v) do { KEEP1((v).x); KEEP1((v).y); } while (0)

__device__ __forceinline__ float sigmoid_(float x) {
    return __builtin_amdgcn_rcpf(1.0f + __expf(-x));
}

__global__ __launch_bounds__(256) void k_pre(const float* __restrict__ f_img,
                                             const float* __restrict__ path,
                                             float* __restrict__ img_out,
                                             float* __restrict__ S) {
    if (blockIdx.x < 4096) {
        // ---- per-(b,c) image mean over 80x80 = 1600 float4 ----
        const int bc = blockIdx.x;
        const float4* p = reinterpret_cast<const float4*>(f_img + (size_t)bc * 6400);
        float s = 0.0f;
        for (int i = threadIdx.x; i < 1600; i += 256) {
            float4 v = p[i];
            s += v.x + v.y + v.z + v.w;
        }
        for (int off = 32; off > 0; off >>= 1) s += __shfl_down(s, off, 64);
        __shared__ float red[4];
        const int wid = threadIdx.x >> 6, lane = threadIdx.x & 63;
        if (lane == 0) red[wid] = s;
        __syncthreads();
        if (threadIdx.x == 0)
            img_out[bc] = (red[0] + red[1] + red[2] + red[3]) * (1.0f / 6400.0f);
    } else {
        // ---- loc sums: one (t,b) per wave, 4 waves/block ----
        const int tb   = (blockIdx.x - 4096) * 4 + (threadIdx.x >> 6);  // t*128 + b
        const int lane = threadIdx.x & 63;
        const float2 v = reinterpret_cast<const float2*>(path)[(size_t)tb * 64 + lane];
        float sx = v.x, sy = v.y;
        for (int off = 32; off > 0; off >>= 1) {
            sx += __shfl_down(sx, off, 64);
            sy += __shfl_down(sy, off, 64);
        }
        if (lane == 0) {
            float2 o; o.x = sx; o.y = sy;
            reinterpret_cast<float2*>(S)[tb] = o;
        }
    }
}

// G0[b][g] = b_ih[g] + (g<96 ? b_hh[g]:0) + img[b].W_ih[g,20:52]
__global__ __launch_bounds__(256) void k_g0(const float* __restrict__ img,
                                            const float* __restrict__ W_ih,
                                            const float* __restrict__ b_ih,
                                            const float* __restrict__ b_hh,
                                            float* __restrict__ G0) {
    const int id = blockIdx.x * 256 + threadIdx.x;
    if (id >= BB * G3) return;
    const int b = id / G3, g = id % G3;
    float acc = b_ih[g] + (g < 96 ? b_hh[g] : 0.0f);
    const float* w = W_ih + g * 52 + 20;
    const float* im = img + b * 32;
#pragma unroll
    for (int c = 0; c < 32; ++c) acc = fmaf(im[c], w[c], acc);
    G0[id] = acc;
}

// Main recurrence. Block = 384 threads = 2 rows x (48 j x 4 K-quarters).
__global__ __launch_bounds__(384) void k_gru(const float* __restrict__ path,
                                             const float* __restrict__ f_vel,
                                             const float* __restrict__ W_ih,
                                             const float* __restrict__ W_hh,
                                             const float* __restrict__ b_hh,
                                             const float* __restrict__ G0,
                                             const float* __restrict__ S,
                                             float* __restrict__ out) {
    const int tid  = threadIdx.x;
    const int r    = tid / 192;      // row slot
    const int q    = tid % 192;
    const int j    = q >> 2;         // gate/hidden index 0..47
    const int s    = q & 3;          // K-quarter
    const int row0 = blockIdx.x * 2;
    const int b    = row0 >> 6;      // batch (both rows same batch)

    __shared__ float gb[T_STEPS][G3];        // per-(t,g) gate constants   23040 B
    __shared__ float xts[2][T_STEPS][20];    // padded x series [lx,ly,0,0,v*16] 6400 B
    __shared__ float olds[2][T_STEPS * HH];  // output buffer             15360 B
    __shared__ float sh[2][2][HH];           // [buf][row][j] hidden        768 B
    __shared__ float w23[G3][2];             // rel-weight cols             1152 B
    __shared__ float sS[T_STEPS][2];         // S[t][b]                      320 B

    // ---- stage small tables ----
    if (tid < G3) {
        w23[tid][0] = W_ih[tid * 52 + 2];
        w23[tid][1] = W_ih[tid * 52 + 3];
    } else if (tid >= 256 && tid < 256 + T_STEPS) {
        const int t = tid - 256;
        const float2 sv = reinterpret_cast<const float2*>(S)[t * BB + b];
        sS[t][0] = sv.x; sS[t][1] = sv.y;
    }
    // ---- stage vel series: 2 rows x 40 t x 16 = 1280 floats ----
    for (int i = tid; i < 2 * T_STEPS * 16; i += 384) {
        const int t = i >> 5, w = i & 31, rr = w >> 4, k = w & 15;
        xts[rr][t][4 + k] = f_vel[((size_t)t * BN + row0 + rr) * 16 + k];
    }
    // ---- stage loc + zero pads: 80 threads ----
    if (tid < 2 * T_STEPS) {
        const int t = tid >> 1, rr = tid & 1;
        const float2 l = reinterpret_cast<const float2*>(path)[(size_t)t * BN + row0 + rr];
        xts[rr][t][0] = l.x; xts[rr][t][1] = l.y;
        xts[rr][t][2] = 0.0f; xts[rr][t][3] = 0.0f;
    }
    // ---- h0 = 0 ----
    if (tid < 2 * HH) sh[0][tid / HH][tid % HH] = 0.0f;

    // ---- weights into registers (independent of LDS; loads overlap staging) ----
    // x-part: padded-20 col c = s*5+p:
    //   c<2 -> W' = W[c] - (64/63)W[c+2]; c=2,3 -> 0 (pads); c>=4 -> W[c]
    const float r63 = 64.0f / 63.0f;
    float wxr[5], wxz[5], wxn[5];
    {
        const float* wr = W_ih + (j)      * 52;
        const float* wz = W_ih + (48 + j) * 52;
        const float* wn = W_ih + (96 + j) * 52;
#pragma unroll
        for (int p = 0; p < 5; ++p) {
            const int c = s * 5 + p;
            if (c >= 4)      { wxr[p] = wr[c]; wxz[p] = wz[c]; wxn[p] = wn[c]; }
            else if (c < 2)  { wxr[p] = wr[c] - r63 * wr[c + 2];
                               wxz[p] = wz[c] - r63 * wz[c + 2];
                               wxn[p] = wn[c] - r63 * wn[c + 2]; }
            else             { wxr[p] = 0.0f; wxz[p] = 0.0f; wxn[p] = 0.0f; }
        }
    }
    float2 whr[6], whz[6], whn[6];   // h-part K-quarter (12 dims) per gate
    {
        const float2* hr  = reinterpret_cast<const float2*>(W_hh + (j)      * 48 + s * 12);
        const float2* hz  = reinterpret_cast<const float2*>(W_hh + (48 + j) * 48 + s * 12);
        const float2* hn_ = reinterpret_cast<const float2*>(W_hh + (96 + j) * 48 + s * 12);
#pragma unroll
        for (int p = 0; p < 6; ++p) { whr[p] = hr[p]; whz[p] = hz[p]; whn[p] = hn_[p]; }
    }
#pragma unroll
    for (int p = 0; p < 5; ++p) { KEEP1(wxr[p]); KEEP1(wxz[p]); KEEP1(wxn[p]); }
#pragma unroll
    for (int p = 0; p < 6; ++p) { KEEP2(whr[p]); KEEP2(whz[p]); KEEP2(whn[p]); }
    const float bhn = b_hh[96 + j];

    __syncthreads();   // w23/sS/xts/sh staged

    // ---- gb[t][g] = G0[b][g] + (Sx*w2 + Sy*w3)/63 ----
    for (int i = tid; i < T_STEPS * G3; i += 384) {
        const int t = i / G3, g = i - t * G3;
        gb[t][g] = G0[b * G3 + g]
                 + (sS[t][0] * w23[g][0] + sS[t][1] * w23[g][1]) * (1.0f / 63.0f);
    }
    __syncthreads();   // gb ready

    const int gidx = (s == 3 ? 0 : s) * 48 + j;   // gb column for this lane's injection

    float hp = 0.0f;   // h_prev for this j (all 4 quarter lanes identical)
    int p = 0;
    for (int t = 0; t < T_STEPS; ++t) {
        // ---- x-part: 5 scalar FMAs per gate ----
        const float* xq = &xts[r][t][s * 5];
        float pr = 0.0f, pz = 0.0f, pn = 0.0f;
#pragma unroll
        for (int pp = 0; pp < 5; ++pp) {
            const float xv = xq[pp];
            pr = fmaf(xv, wxr[pp], pr);
            pz = fmaf(xv, wxz[pp], pz);
            pn = fmaf(xv, wxn[pp], pn);
        }
        // ---- h-part: 6 float2 FMAs per gate ----
        const float2* hq = reinterpret_cast<const float2*>(&sh[p][r][s * 12]);
        float2 hr2 = {0.f, 0.f}, hz2 = {0.f, 0.f}, hn2 = {0.f, 0.f};
#pragma unroll
        for (int pp = 0; pp < 6; ++pp) {
            const float2 hv = hq[pp];
            hr2.x = fmaf(hv.x, whr[pp].x, hr2.x); hr2.y = fmaf(hv.y, whr[pp].y, hr2.y);
            hz2.x = fmaf(hv.x, whz[pp].x, hz2.x); hz2.y = fmaf(hv.y, whz[pp].y, hz2.y);
            hn2.x = fmaf(hv.x, whn[pp].x, hn2.x); hn2.y = fmaf(hv.y, whn[pp].y, hn2.y);
        }
        // ---- inject gb constants pre-reduce (one lane each; butterfly spreads) ----
        const float gcur = gb[t][gidx];
        float ar  = pr + hr2.x + hr2.y + (s == 0 ? gcur : 0.0f);
        float az  = pz + hz2.x + hz2.y + (s == 1 ? gcur : 0.0f);
        float ani = pn                 + (s == 2 ? gcur : 0.0f);
        float anh = hn2.x + hn2.y;
        // ---- butterfly reduce across the 4 quarter lanes ----
        ar  += __shfl_xor(ar, 1, 64);  ar  += __shfl_xor(ar, 2, 64);
        az  += __shfl_xor(az, 1, 64);  az  += __shfl_xor(az, 2, 64);
        ani += __shfl_xor(ani, 1, 64); ani += __shfl_xor(ani, 2, 64);
        anh += __shfl_xor(anh, 1, 64); anh += __shfl_xor(anh, 2, 64);

        const float rg = sigmoid_(ar);        // biases already inside gb
        const float zg = sigmoid_(az);
        float a = ani + rg * (anh + bhn);
        a = fminf(fmaxf(a, -15.0f), 15.0f);
        const float e = __expf(-2.0f * a);
        const float cand = (1.0f - e) * __builtin_amdgcn_rcpf(1.0f + e);
        const float hn = zg * (hp - cand) + cand;   // (1-z)*cand + z*h

        if (s == 0) {
            sh[p ^ 1][r][j] = hn;               // other buffer: no pre-write hazard
        } else if (s == 1) {
            olds[r][t * HH + j] = hn;           // LDS output buffer (no global!)
        }
        hp = hn;
        p ^= 1;
        __syncthreads();   // publish sh[p^1] (+ last iter: olds for the flush)
    }

    // ---- flush outputs: 2 rows x 40 t x 48 = 3840 floats, coalesced ----
    for (int i = tid; i < 2 * T_STEPS * HH; i += 384) {
        const int t = i / 96, w = i - t * 96, rr = w / 48, jj = w - rr * 48;
        out[((size_t)t * BN + row0 + rr) * HH + jj] = olds[rr][t * HH + jj];
    }
    if (tid < 2 * HH) {   // hT = h at t=39
        const int rr = tid / 48, jj = tid % 48;
        out[(size_t)T_STEPS * BN * HH + (size_t)(row0 + rr) * HH + jj]
            = olds[rr][(T_STEPS - 1) * HH + jj];
    }
}

extern "C" void kernel_launch(void* const* d_in, const int* in_sizes, int n_in,
                              void* d_out, int out_size, void* d_ws, size_t ws_size,
                              hipStream_t stream) {
    const float* path  = (const float*)d_in[0];
    const float* f_vel = (const float*)d_in[1];
    const float* f_img = (const float*)d_in[2];
    const float* W_ih  = (const float*)d_in[3];
    const float* W_hh  = (const float*)d_in[4];
    const float* b_ih  = (const float*)d_in[5];
    const float* b_hh  = (const float*)d_in[6];
    float* out = (float*)d_out;

    float* ws  = (float*)d_ws;
    float* img = ws;                  // 4096 floats
    float* G0  = ws + 4096;           // 18432 floats
    float* S   = ws + 4096 + 18432;   // 10240 floats   (total 128 KB, known-good)

    hipLaunchKernelGGL(k_pre, dim3(4096 + (T_STEPS * BB) / 4), dim3(256), 0, stream,
                       f_img, path, img, S);
    hipLaunchKernelGGL(k_g0, dim3((BB * G3 + 255) / 256), dim3(256), 0, stream,
                       img, W_ih, b_ih, b_hh, G0);
    hipLaunchKernelGGL(k_gru, dim3(BN / 2), dim3(384), 0, stream,
                       path, f_vel, W_ih, W_hh, b_hh, G0, S, out);
}

// Round 8
// 289.370 us; speedup vs baseline: 1.7809x; 1.6384x over previous
//
#include <hip/hip_runtime.h>

// SCF GRU layer: T=40, B=128, N=64, H=48. BN=8192 rows.
// R0-R7 lesson: every scalar-VALU formulation (weights per-thread) lands at
// 238-350us because the allocator caps arch VGPRs (~44-84) and shelves the
// weights into AGPRs with per-step copy storms; barriers + LDS latency set a
// ~2000cyc/step critical path. This round switches to MFMA (Guideline 10):
// per step the op is [16x20]@Wx^T + [16x48]@Wh^T per 16-row wave -> 81
// v_mfma_f32_16x16x32_bf16 per wave-step, weights amortized across rows,
// hi/lo bf16 split (3 terms) for fp32-grade accuracy, fp32 epilogue.
// One wave per block, 16 rows, self-contained: NO barriers in the t-loop;
// h recycles via a 4.6KB LDS bounce (wave-internal lgkmcnt ordering).
// W fragments live in the unified RF's AGPR half (MFMA-only operands);
// amdgpu_waves_per_eu(1,1) grants the 512-reg budget. Occupancy is
// intentionally 1 wave/SIMD, 2 blocks/CU (512 blocks on 256 CUs).

#define T_STEPS 40
#define BB      128
#define HH      48
#define BN      8192
#define G3      144

typedef __attribute__((ext_vector_type(8))) short bf16x8;
typedef __attribute__((ext_vector_type(4))) float f32x4;
#define MFMA16 __builtin_amdgcn_mfma_f32_16x16x32_bf16

__device__ __forceinline__ float sigmoid_(float x) {
    return __builtin_amdgcn_rcpf(1.0f + __expf(-x));
}
__device__ __forceinline__ unsigned short bf16rne(float x) {
    unsigned u = __builtin_bit_cast(unsigned, x);
    u += 0x7FFFu + ((u >> 16) & 1u);
    return (unsigned short)(u >> 16);
}
__device__ __forceinline__ void bf16split(float x, unsigned short& h, unsigned short& l) {
    h = bf16rne(x);
    const float hf = __builtin_bit_cast(float, (unsigned)h << 16);
    l = bf16rne(x - hf);
}

__global__ __launch_bounds__(256) void k_pre(const float* __restrict__ f_img,
                                             const float* __restrict__ path,
                                             float* __restrict__ img_out,
                                             float* __restrict__ S) {
    if (blockIdx.x < 4096) {
        const int bc = blockIdx.x;
        const float4* p = reinterpret_cast<const float4*>(f_img + (size_t)bc * 6400);
        float s = 0.0f;
        for (int i = threadIdx.x; i < 1600; i += 256) {
            float4 v = p[i];
            s += v.x + v.y + v.z + v.w;
        }
        for (int off = 32; off > 0; off >>= 1) s += __shfl_down(s, off, 64);
        __shared__ float red[4];
        const int wid = threadIdx.x >> 6, lane = threadIdx.x & 63;
        if (lane == 0) red[wid] = s;
        __syncthreads();
        if (threadIdx.x == 0)
            img_out[bc] = (red[0] + red[1] + red[2] + red[3]) * (1.0f / 6400.0f);
    } else {
        const int tb   = (blockIdx.x - 4096) * 4 + (threadIdx.x >> 6);
        const int lane = threadIdx.x & 63;
        const float2 v = reinterpret_cast<const float2*>(path)[(size_t)tb * 64 + lane];
        float sx = v.x, sy = v.y;
        for (int off = 32; off > 0; off >>= 1) {
            sx += __shfl_down(sx, off, 64);
            sy += __shfl_down(sy, off, 64);
        }
        if (lane == 0) {
            float2 o; o.x = sx; o.y = sy;
            reinterpret_cast<float2*>(S)[tb] = o;
        }
    }
}

// G0[b][g] = b_ih[g] + (g<96 ? b_hh[g]:0) + img[b].W_ih[g,20:52]
__global__ __launch_bounds__(256) void k_g0(const float* __restrict__ img,
                                            const float* __restrict__ W_ih,
                                            const float* __restrict__ b_ih,
                                            const float* __restrict__ b_hh,
                                            float* __restrict__ G0) {
    const int id = blockIdx.x * 256 + threadIdx.x;
    if (id >= BB * G3) return;
    const int b = id / G3, g = id % G3;
    float acc = b_ih[g] + (g < 96 ? b_hh[g] : 0.0f);
    const float* w = W_ih + g * 52 + 20;
    const float* im = img + b * 32;
#pragma unroll
    for (int c = 0; c < 32; ++c) acc = fmaf(im[c], w[c], acc);
    G0[id] = acc;
}

// One wave = 16 rows. lane l: c = l&15 (row for A / gate-col for B/C),
// gq = l>>4 (k-group). MFMA layouts (16x16x32 bf16):
//   A: row=c, k=8*gq+e ; B: col=c, k=8*gq+e ; C: col=c, row=4*gq+reg (m89-verified).
__global__ __launch_bounds__(64) __attribute__((amdgpu_waves_per_eu(1, 1)))
void k_gru(const float* __restrict__ path,
           const float* __restrict__ f_vel,
           const float* __restrict__ W_ih,
           const float* __restrict__ W_hh,
           const float* __restrict__ b_hh,
           const float* __restrict__ G0,
           const float* __restrict__ S,
           float* __restrict__ out) {
    const int l  = threadIdx.x;
    const int c  = l & 15;
    const int gq = l >> 4;
    const int row0 = blockIdx.x * 16;
    const int b    = row0 >> 6;
    const int R    = row0 + c;

    __shared__ unsigned short hHI[16 * 72];   // h_{t-1} hi-bf16, stride 72 (bank-spread)
    __shared__ unsigned short hLO[16 * 72];   // h_{t-1} lo-bf16
    __shared__ float sS[T_STEPS][2];          // S[t][b] / 63

    for (int i = l; i < 16 * 72; i += 64) { hHI[i] = 0; hLO[i] = 0; }
    if (l < T_STEPS) {
        const float2 sv = reinterpret_cast<const float2*>(S)[l * BB + b];
        sS[l][0] = sv.x * (1.0f / 63.0f);
        sS[l][1] = sv.y * (1.0f / 63.0f);
    }

    // per-lane gate-column constants (9 cols: jt*16+c covers r,z,n)
    float g0v[9], bhnv[3];
#pragma unroll
    for (int jt = 0; jt < 9; ++jt) g0v[jt] = G0[b * G3 + jt * 16 + c];
#pragma unroll
    for (int jt = 0; jt < 3; ++jt) bhnv[jt] = b_hh[96 + jt * 16 + c];

    // ---- resident W fragments (MFMA-only operands -> AGPR half of the RF) ----
    // X K-layout (20 used): [locx', locy', W2, W3, vel0..15]; W'=W-(64/63)W[.+2]
    bf16x8 wxhi[9], wxlo[9], whhi[9][2], whlo[9][2];
    const float r63 = 64.0f / 63.0f;
#pragma unroll
    for (int jt = 0; jt < 9; ++jt) {
        const int g = jt * 16 + c;
        const float* wr = W_ih + g * 52;
#pragma unroll
        for (int e = 0; e < 8; ++e) {
            const int k = gq * 8 + e;
            float v = (k < 20) ? wr[k] : 0.0f;
            if (k < 2) v -= r63 * wr[k + 2];
            unsigned short h_, l_; bf16split(v, h_, l_);
            wxhi[jt][e] = (short)h_; wxlo[jt][e] = (short)l_;
        }
        const float* hr = W_hh + g * 48;
#pragma unroll
        for (int ch = 0; ch < 2; ++ch)
#pragma unroll
            for (int e = 0; e < 8; ++e) {
                const int k = ch * 32 + gq * 8 + e;
                float v = (k < 48) ? hr[k] : 0.0f;
                unsigned short h_, l_; bf16split(v, h_, l_);
                whhi[jt][ch][e] = (short)h_; whlo[jt][ch][e] = (short)l_;
            }
    }

    int obase[4];
#pragma unroll
    for (int i = 0; i < 4; ++i) obase[i] = (row0 + gq * 4 + i) * HH + c;

    __syncthreads();   // hHI/hLO zeroed, sS staged

    const float2* path2 = reinterpret_cast<const float2*>(path);
    const float4* vel4  = reinterpret_cast<const float4*>(f_vel);

    // raw x for t=0 (per k-group)
    float2 lc = {0.f, 0.f}; float4 va = {0.f, 0.f, 0.f, 0.f}, vb = va;
    if (gq == 0)      { lc = path2[R]; va = vel4[(size_t)R * 4]; }
    else if (gq == 1) { va = vel4[(size_t)R * 4 + 1]; vb = vel4[(size_t)R * 4 + 2]; }
    else if (gq == 2) { va = vel4[(size_t)R * 4 + 3]; }

    float hp[3][4];
#pragma unroll
    for (int jt = 0; jt < 3; ++jt)
#pragma unroll
        for (int i = 0; i < 4; ++i) hp[jt][i] = 0.0f;

    const f32x4 zf = {0.f, 0.f, 0.f, 0.f};
    const bf16x8 z8 = {0, 0, 0, 0, 0, 0, 0, 0};

    for (int t = 0; t < T_STEPS; ++t) {
        // ---- A_h fragments from LDS (h_{t-1}; zeros at t=0) ----
        asm volatile("s_waitcnt lgkmcnt(0)" ::: "memory");
        __builtin_amdgcn_sched_barrier(0);
        bf16x8 ah0h = *(const bf16x8*)&hHI[c * 72 + gq * 8];
        bf16x8 ah0l = *(const bf16x8*)&hLO[c * 72 + gq * 8];
        bf16x8 ah1h = z8, ah1l = z8;
        if (gq < 2) {
            ah1h = *(const bf16x8*)&hHI[c * 72 + 32 + gq * 8];
            ah1l = *(const bf16x8*)&hLO[c * 72 + 32 + gq * 8];
        }

        // ---- A_x fragments from raw regs ----
        float xv[8];
        if (gq == 0) {
            xv[0] = lc.x; xv[1] = lc.y; xv[2] = sS[t][0]; xv[3] = sS[t][1];
            xv[4] = va.x; xv[5] = va.y; xv[6] = va.z; xv[7] = va.w;
        } else if (gq == 1) {
            xv[0] = va.x; xv[1] = va.y; xv[2] = va.z; xv[3] = va.w;
            xv[4] = vb.x; xv[5] = vb.y; xv[6] = vb.z; xv[7] = vb.w;
        } else if (gq == 2) {
            xv[0] = va.x; xv[1] = va.y; xv[2] = va.z; xv[3] = va.w;
            xv[4] = 0.f; xv[5] = 0.f; xv[6] = 0.f; xv[7] = 0.f;
        } else {
#pragma unroll
            for (int e = 0; e < 8; ++e) xv[e] = 0.f;
        }
        bf16x8 axh, axl;
#pragma unroll
        for (int e = 0; e < 8; ++e) {
            unsigned short h_, l_; bf16split(xv[e], h_, l_);
            axh[e] = (short)h_; axl[e] = (short)l_;
        }

        // ---- prefetch raw x for t+1 (hides under MFMA + epilogue) ----
        if (t + 1 < T_STEPS) {
            const size_t base = (size_t)(t + 1) * BN + R;
            if (gq == 0)      { lc = path2[base]; va = vel4[base * 4]; }
            else if (gq == 1) { va = vel4[base * 4 + 1]; vb = vel4[base * 4 + 2]; }
            else if (gq == 2) { va = vel4[base * 4 + 3]; }
        }

        // ---- MFMAs: 27 (X) + 54 (H), hi/lo 3-term compensation ----
        f32x4 accX[9], accH[9];
#pragma unroll
        for (int jt = 0; jt < 9; ++jt) {
            f32x4 a = MFMA16(axh, wxhi[jt], zf, 0, 0, 0);
            a = MFMA16(axl, wxhi[jt], a, 0, 0, 0);
            a = MFMA16(axh, wxlo[jt], a, 0, 0, 0);
            accX[jt] = a;
            f32x4 h = MFMA16(ah0h, whhi[jt][0], zf, 0, 0, 0);
            h = MFMA16(ah0l, whhi[jt][0], h, 0, 0, 0);
            h = MFMA16(ah0h, whlo[jt][0], h, 0, 0, 0);
            h = MFMA16(ah1h, whhi[jt][1], h, 0, 0, 0);
            h = MFMA16(ah1l, whhi[jt][1], h, 0, 0, 0);
            h = MFMA16(ah1h, whlo[jt][1], h, 0, 0, 0);
            accH[jt] = h;
        }

        // ---- epilogue: 12 h-values per lane, fp32 ----
#pragma unroll
        for (int jt = 0; jt < 3; ++jt)
#pragma unroll
            for (int i = 0; i < 4; ++i) {
                const float gr  = accX[jt][i]     + accH[jt][i]     + g0v[jt];
                const float gz  = accX[jt + 3][i] + accH[jt + 3][i] + g0v[jt + 3];
                const float gin = accX[jt + 6][i] + g0v[jt + 6];
                const float ghn = accH[jt + 6][i] + bhnv[jt];
                const float rg = sigmoid_(gr);
                const float zg = sigmoid_(gz);
                float a2 = gin + rg * ghn;
                a2 = fminf(fmaxf(a2, -15.0f), 15.0f);
                const float e2 = __expf(-2.0f * a2);
                const float cand = (1.0f - e2) * __builtin_amdgcn_rcpf(1.0f + e2);
                const float hn = zg * (hp[jt][i] - cand) + cand;
                hp[jt][i] = hn;
                out[(size_t)t * BN * HH + obase[i] + jt * 16] = hn;
                if (t == T_STEPS - 1)
                    out[(size_t)T_STEPS * BN * HH + obase[i] + jt * 16] = hn;
                unsigned short hh_, hl_; bf16split(hn, hh_, hl_);
                const int widx = (gq * 4 + i) * 72 + jt * 16 + c;
                hHI[widx] = hh_; hLO[widx] = hl_;
            }
    }
}

extern "C" void kernel_launch(void* const* d_in, const int* in_sizes, int n_in,
                              void* d_out, int out_size, void* d_ws, size_t ws_size,
                              hipStream_t stream) {
    const float* path  = (const float*)d_in[0];
    const float* f_vel = (const float*)d_in[1];
    const float* f_img = (const float*)d_in[2];
    const float* W_ih  = (const float*)d_in[3];
    const float* W_hh  = (const float*)d_in[4];
    const float* b_ih  = (const float*)d_in[5];
    const float* b_hh  = (const float*)d_in[6];
    float* out = (float*)d_out;

    float* ws  = (float*)d_ws;
    float* img = ws;                  // 4096 floats
    float* G0  = ws + 4096;           // 18432 floats
    float* S   = ws + 4096 + 18432;   // 10240 floats  (128 KB total, known-good)

    hipLaunchKernelGGL(k_pre, dim3(4096 + (T_STEPS * BB) / 4), dim3(256), 0, stream,
                       f_img, path, img, S);
    hipLaunchKernelGGL(k_g0, dim3((BB * G3 + 255) / 256), dim3(256), 0, stream,
                       img, W_ih, b_ih, b_hh, G0);
    hipLaunchKernelGGL(k_gru, dim3(BN / 16), dim3(64), 0, stream,
                       path, f_vel, W_ih, W_hh, b_hh, G0, S, out);
}